// Round 6
// baseline (217.074 us; speedup 1.0000x reference)
//
#include <hip/hip_runtime.h>
#include <math.h>

// Problem: B=16, N=2049, C=1024, w_qkv is (1024, 3072) row-major.
// out = softmax over n of  scale * (x[b,0,:] @ Wq) . (x[b,n+1,:] @ Wk)
// Reassociated: q_cls[b] = Wq^T x[b,0,:];  v[b] = Wk @ q_cls[b];
//               logit[b,n] = scale * x[b,n+1,:] . v[b]
//
// Round-5 (215.7us) structure kept verbatim; this round is per-kernel
// micro-efficiency only (lesson: fusion never pays; gaps are ~1-2us):
//   A2: float4 loads (1KB/wave-instr, was 256B), 4096 threads.
//   V : 256 blocks x 1 row/wave (was 128 x 2) -- halves serial tail.
//   K3: 4096 blocks x 2 rows/wave -- halves v-stage+barrier overhead,
//       2 independent dot/reduce chains per wave for ILP.
// K1/K4 unchanged (verified at their latency floor).

#define BATCH 16
#define SEQ   2049
#define CH    1024
#define W3    3072
#define NOUT  2048

// ws layout (floats):
//   part   : [0, 64*16*1024) = 1048576  (4 MB)
//   qcls   : [1048576, +16384)
//   v      : [1064960, +16384)
//   logits : [1081344, +32768)

// ---------------- K1: q_cls partials ----------------
// grid (4 colchunks, 64 dchunks), block 256 (4 waves).
// Block (ci,pi): Wq tile rows [pi*16,+16) x cols [ci*256,+256).
// Wave w owns rows pi*16 + w*4 + (0..3); per-row load = 64 lanes x float4
// = 1KB coalesced. Wq read exactly once chip-wide (4 MB). 2-phase LDS
// reduce across the 4 waves -> same 64-partial layout as the baseline.
__global__ __launch_bounds__(256) void qcls_partial_kernel(
    const float* __restrict__ x, const float* __restrict__ w,
    float* __restrict__ part) {
    const int ci = blockIdx.x;          // 0..3
    const int pi = blockIdx.y;          // 0..63
    const int t  = threadIdx.x;
    const int lane = t & 63;
    const int wv   = t >> 6;            // 0..3

    __shared__ float  xs[BATCH][16];    // 1 KB: xs[b][dd] = x[b,0,pi*16+dd]
    __shared__ float4 red[4][8][64];    // 32 KB

    {   // 256 threads cover 16x16 exactly
        const int b = t >> 4, dd = t & 15;
        xs[b][dd] = x[(size_t)b * SEQ * CH + pi * 16 + dd];
    }
    __syncthreads();

    const int c = ci * 256 + lane * 4;
    float4 acc[BATCH];
    #pragma unroll
    for (int b = 0; b < BATCH; ++b) acc[b] = {0.f, 0.f, 0.f, 0.f};

    const int drow0 = pi * 16 + wv * 4;
    #pragma unroll
    for (int dd = 0; dd < 4; ++dd) {
        const float4 wvec = *(const float4*)(w + (size_t)(drow0 + dd) * W3 + c);
        const float s0 = xs[0][wv * 4 + dd];
        acc[0].x += s0 * wvec.x; acc[0].y += s0 * wvec.y;
        acc[0].z += s0 * wvec.z; acc[0].w += s0 * wvec.w;
        #pragma unroll
        for (int b = 1; b < BATCH; ++b) {
            const float s = xs[b][wv * 4 + dd];
            acc[b].x += s * wvec.x; acc[b].y += s * wvec.y;
            acc[b].z += s * wvec.z; acc[b].w += s * wvec.w;
        }
    }

    // 2-phase cross-wave reduce; wave w owns batches (w*2, w*2+1) per phase.
    #pragma unroll
    for (int p = 0; p < 2; ++p) {
        __syncthreads();                 // protect prior-phase reads
        #pragma unroll
        for (int b2 = 0; b2 < 8; ++b2)
            red[wv][b2][lane] = acc[p * 8 + b2];
        __syncthreads();
        #pragma unroll
        for (int k = 0; k < 2; ++k) {
            const int b2 = wv * 2 + k;
            float4 s = red[0][b2][lane];
            #pragma unroll
            for (int ww = 1; ww < 4; ++ww) {
                const float4 r = red[ww][b2][lane];
                s.x += r.x; s.y += r.y; s.z += r.z; s.w += r.w;
            }
            *(float4*)(part + ((size_t)pi * BATCH + p * 8 + b2) * CH + c) = s;
        }
    }
}

// ---------------- K2a: reduce 64 partials -> q_cls ----------------
// grid 64, block 64. One float4 quad per thread (4096 quads total);
// 1KB/wave-instruction coalescing; p-ascending order = bitwise-identical
// to the scalar version.
__global__ __launch_bounds__(64) void qcls_reduce_kernel(
    const float* __restrict__ part, float* __restrict__ qcls) {
    const int q = blockIdx.x * 64 + threadIdx.x;     // quad id, 0..4095
    const float4* p4 = (const float4*)part;
    float4 s = p4[q];
    #pragma unroll 8
    for (int p = 1; p < 64; ++p) {
        const float4 r = p4[(size_t)p * (BATCH * CH / 4) + q];
        s.x += r.x; s.y += r.y; s.z += r.z; s.w += r.w;
    }
    ((float4*)qcls)[q] = s;
}

// ---------------- K2b: v[b,d] = Wk[d,:] . q_cls[b,:] ----------------
// grid 256, block 256 (4 waves, ONE d-row each). q_cls (64 KB) staged in
// LDS. Lanes span c (coalesced float4), shuffle-reduce per batch.
__global__ __launch_bounds__(256) void v_kernel(
    const float* __restrict__ w, const float* __restrict__ qcls,
    float* __restrict__ v) {
    __shared__ float qs[BATCH * CH];   // 64 KB
    const int t = threadIdx.x;
    for (int i = t; i < BATCH * CH; i += 256) qs[i] = qcls[i];
    __syncthreads();
    const int lane = t & 63;
    const int wave = t >> 6;
    const int d = blockIdx.x * 4 + wave;            // 0..1023
    const float* wrow = w + (size_t)d * W3 + CH;    // Wk = cols [1024,2048)
    float4 wv4[4];
    #pragma unroll
    for (int j = 0; j < 4; ++j)
        wv4[j] = *(const float4*)(wrow + lane * 4 + j * 256);
    #pragma unroll
    for (int b = 0; b < BATCH; ++b) {
        float acc = 0.f;
        #pragma unroll
        for (int j = 0; j < 4; ++j) {
            const float4 qv = *(const float4*)(&qs[b * CH + lane * 4 + j * 256]);
            acc += wv4[j].x * qv.x + wv4[j].y * qv.y
                 + wv4[j].z * qv.z + wv4[j].w * qv.w;
        }
        #pragma unroll
        for (int off = 32; off > 0; off >>= 1)
            acc += __shfl_down(acc, off, 64);
        if (lane == 0) v[b * CH + d] = acc;
    }
}

// ---------------- K3: logits (the memory-bound streamer) ----------------
// grid 4096 x 256: block = 8 rows of ONE batch (2048 % 8 == 0); each wave
// handles 2 consecutive rows (independent dot/reduce chains for ILP).
// v[b] staged once per block in LDS (4 KB).
__global__ __launch_bounds__(256) void logits_kernel(
    const float* __restrict__ x, const float* __restrict__ v,
    float* __restrict__ logits) {
    const int t = threadIdx.x;
    const int lane = t & 63;
    const int rbase = blockIdx.x * 8;
    const int b = rbase >> 11;         // constant within block

    __shared__ float4 vs[CH / 4];      // 4 KB
    vs[t] = ((const float4*)(v + (size_t)b * CH))[t];
    __syncthreads();

    const int row = rbase + (t >> 6) * 2;       // wave's first row (even)
    const int n = row & (NOUT - 1);             // 0..2046, even
    const float* xrowA = x + ((size_t)b * SEQ + n + 1) * CH;
    const float* xrowB = xrowA + CH;            // next row, same batch
    float accA = 0.f, accB = 0.f;
    #pragma unroll
    for (int j = 0; j < 4; ++j) {
        const float4 xa = *(const float4*)(xrowA + lane * 4 + j * 256);
        const float4 xb = *(const float4*)(xrowB + lane * 4 + j * 256);
        const float4 vv = vs[lane + j * 64];
        accA += xa.x * vv.x + xa.y * vv.y + xa.z * vv.z + xa.w * vv.w;
        accB += xb.x * vv.x + xb.y * vv.y + xb.z * vv.z + xb.w * vv.w;
    }
    #pragma unroll
    for (int off = 32; off > 0; off >>= 1) {
        accA += __shfl_down(accA, off, 64);
        accB += __shfl_down(accB, off, 64);
    }
    if (lane == 0) {
        logits[row]     = accA * 0.03125f;      // scale = C^-0.5 = 1/32
        logits[row + 1] = accB * 0.03125f;
    }
}

// ---------------- K4: softmax over 2048 per batch ----------------
// 256 threads = 4 waves; shuffle reduce within wave, tiny LDS across waves.
__global__ __launch_bounds__(256) void softmax_kernel(
    const float* __restrict__ logits, float* __restrict__ out) {
    const int b = blockIdx.x;
    const int t = threadIdx.x;
    const int lane = t & 63;
    const int wv = t >> 6;
    __shared__ float wred[4];

    float val[8];
    float m = -1e30f;
    #pragma unroll
    for (int i = 0; i < 8; ++i) {
        val[i] = logits[b * NOUT + t + i * 256];
        m = fmaxf(m, val[i]);
    }
    #pragma unroll
    for (int off = 32; off > 0; off >>= 1)
        m = fmaxf(m, __shfl_xor(m, off, 64));
    if (lane == 0) wred[wv] = m;
    __syncthreads();
    const float mx = fmaxf(fmaxf(wred[0], wred[1]), fmaxf(wred[2], wred[3]));
    __syncthreads();                    // before wred reuse

    float e[8];
    float sum = 0.f;
    #pragma unroll
    for (int i = 0; i < 8; ++i) { e[i] = expf(val[i] - mx); sum += e[i]; }
    #pragma unroll
    for (int off = 32; off > 0; off >>= 1)
        sum += __shfl_xor(sum, off, 64);
    if (lane == 0) wred[wv] = sum;
    __syncthreads();
    const float inv = 1.0f / (wred[0] + wred[1] + wred[2] + wred[3]);
    #pragma unroll
    for (int i = 0; i < 8; ++i) out[b * NOUT + t + i * 256] = e[i] * inv;
}

extern "C" void kernel_launch(void* const* d_in, const int* in_sizes, int n_in,
                              void* d_out, int out_size, void* d_ws, size_t ws_size,
                              hipStream_t stream) {
    const float* x = (const float*)d_in[0];   // (16, 2049, 1024) fp32
    const float* w = (const float*)d_in[1];   // (1024, 3072) fp32
    float* out = (float*)d_out;               // (16, 2048) fp32
    float* ws = (float*)d_ws;

    float* part   = ws;                        // 1,048,576 floats (4 MB)
    float* qcls   = ws + 1048576;              // 16384 floats
    float* vbuf   = ws + 1048576 + 16384;      // 16384 floats
    float* logits = ws + 1048576 + 32768;      // 32768 floats

    qcls_partial_kernel<<<dim3(4, 64), 256, 0, stream>>>(x, w, part);
    qcls_reduce_kernel<<<64, 64, 0, stream>>>(part, qcls);
    v_kernel<<<256, 256, 0, stream>>>(w, qcls, vbuf);
    logits_kernel<<<4096, 256, 0, stream>>>(x, vbuf, logits);
    softmax_kernel<<<BATCH, 256, 0, stream>>>(logits, out);
}